// Round 5
// baseline (551.029 us; speedup 1.0000x reference)
//
#include <hip/hip_runtime.h>

typedef __bf16 bf16x8 __attribute__((ext_vector_type(8)));
typedef float f32x4 __attribute__((ext_vector_type(4)));
typedef float f32x16 __attribute__((ext_vector_type(16)));

#define MFMA16(a, b, c) __builtin_amdgcn_mfma_f32_16x16x32_bf16(a, b, c, 0, 0, 0)
#define MFMA32(a, b, c) __builtin_amdgcn_mfma_f32_32x32x16_bf16(a, b, c, 0, 0, 0)
#define LOG2E 1.44269504088896340736f

__device__ __forceinline__ unsigned short f2bf(float f) {
  union { float f; unsigned u; } v; v.f = f;
  return (unsigned short)((v.u + 0x7fffu + ((v.u >> 16) & 1u)) >> 16);
}
__device__ __forceinline__ bf16x8 ld_frag(const unsigned short* p) {
  return *(const bf16x8*)p;  // 16B-aligned by construction
}
__device__ __forceinline__ void gld_lds16(const unsigned short* g, unsigned short* l) {
  __builtin_amdgcn_global_load_lds(
      (const __attribute__((address_space(1))) unsigned int*)(const void*)g,
      (__attribute__((address_space(3))) unsigned int*)(void*)l, 16, 0, 0);
}

// fp32 -> bf16, 4 elements/thread
__global__ void cvt_f2bf(const float* __restrict__ in,
                         unsigned short* __restrict__ out, int n4) {
  int i = blockIdx.x * blockDim.x + threadIdx.x;
  if (i < n4) {
    float4 v = ((const float4*)in)[i];
    ushort4 o;
    o.x = f2bf(v.x); o.y = f2bf(v.y); o.z = f2bf(v.z); o.w = f2bf(v.w);
    ((ushort4*)out)[i] = o;
  }
}

// ---------------------------------------------------------------------------
// C[M,N] = A[M,K] * B[N,K]^T + bias[N]   (A,B bf16; bias fp32)
// mode 0: store fp32 to outf[M,N]
// mode 1: QKV split: n<512 -> qbuf; n<1024 -> kbuf; else transposed vtbuf[b][d][s]
// 128x128 tile, BK=32, 256 threads, 4 waves in 2x2, wave tile 64x64.
// ---------------------------------------------------------------------------
__global__ void gemm_bt(const unsigned short* __restrict__ A,
                        const unsigned short* __restrict__ B,
                        const float* __restrict__ bias,
                        float* __restrict__ outf,
                        unsigned short* __restrict__ qbuf,
                        unsigned short* __restrict__ kbuf,
                        unsigned short* __restrict__ vtbuf,
                        int M, int N, int K, int mode) {
  __shared__ alignas(16) unsigned short As[128 * 32];
  __shared__ alignas(16) unsigned short Bs[128 * 32];
  const int n0 = blockIdx.x * 128, m0 = blockIdx.y * 128;
  const int tid = threadIdx.x;
  const int l = tid & 63, w = tid >> 6;
  const int quad = l >> 4, c = l & 15;
  const int wm = (w >> 1) * 64, wn = (w & 1) * 64;

  f32x4 acc[4][4] = {};
  const int kiters = K >> 5;
  for (int kt = 0; kt < kiters; ++kt) {
    __syncthreads();
    const int kk = kt * 32 + (l & 3) * 8;
    const int row = l >> 2;
#pragma unroll
    for (int i = 0; i < 2; ++i) {
      const int rbase = i * 64 + w * 16;
      gld_lds16(&A[(size_t)(m0 + rbase + row) * K + kk], &As[rbase * 32]);
      gld_lds16(&B[(size_t)(n0 + rbase + row) * K + kk], &Bs[rbase * 32]);
    }
    __syncthreads();
    bf16x8 af[4], bfr[4];
#pragma unroll
    for (int t = 0; t < 4; ++t) {
      af[t] = ld_frag(&As[(wm + t * 16 + c) * 32 + quad * 8]);
      bfr[t] = ld_frag(&Bs[(wn + t * 16 + c) * 32 + quad * 8]);
    }
#pragma unroll
    for (int mt = 0; mt < 4; ++mt)
#pragma unroll
      for (int nt = 0; nt < 4; ++nt)
        acc[mt][nt] = MFMA16(af[mt], bfr[nt], acc[mt][nt]);
  }

#pragma unroll
  for (int nt = 0; nt < 4; ++nt) {
    const int n = n0 + wn + nt * 16 + c;
    const float bsum = bias[n];
#pragma unroll
    for (int mt = 0; mt < 4; ++mt) {
      const int mbase = m0 + wm + mt * 16 + quad * 4;
      if (mode == 0) {
#pragma unroll
        for (int r = 0; r < 4; ++r)
          outf[(size_t)(mbase + r) * N + n] = acc[mt][nt][r] + bsum;
      } else if (n < 1024) {
        unsigned short* dst = (n < 512) ? qbuf : kbuf;
        const int nn = n & 511;
#pragma unroll
        for (int r = 0; r < 4; ++r)
          dst[(size_t)(mbase + r) * 512 + nn] = f2bf(acc[mt][nt][r] + bsum);
      } else {
        const int d = n - 1024;
        const int bb = mbase >> 12, s = mbase & 4095;
        ushort4 pk;
        pk.x = f2bf(acc[mt][nt][0] + bsum);
        pk.y = f2bf(acc[mt][nt][1] + bsum);
        pk.z = f2bf(acc[mt][nt][2] + bsum);
        pk.w = f2bf(acc[mt][nt][3] + bsum);
        *(ushort4*)&vtbuf[((size_t)bb * 512 + d) * 4096 + s] = pk;
      }
    }
  }
}

// ---------------------------------------------------------------------------
// Flash attention, 32x32x16 MFMA, transposed-S, kv-split-2.
// Grid 512 = 4b x 64qt x 2 kv-halves; block: 64 q x 2048 kv (64 iters of 32).
// Wave (qh,kh): S^T[32kv x 32q(qh)] over k-half kh (partial, f32-exchanged
// through scratch overlaid on dead k_lds), then O^T[256d(kh) x 32q(qh)].
// 2 blocks/CU; LDS 71168 B.
// ---------------------------------------------------------------------------
#define KROW 520
#define PROW 40

__global__ __launch_bounds__(256, 2) void attn_kernel(
    const unsigned short* __restrict__ Q, const unsigned short* __restrict__ Kb,
    const unsigned short* __restrict__ Vt, unsigned short* __restrict__ part0,
    unsigned short* __restrict__ part1, float2* __restrict__ mlbuf) {
  __shared__ alignas(16) unsigned short k_lds[32 * KROW];  // 33.3 KB; first 16 KB doubles as exchange
  __shared__ alignas(16) unsigned short v_lds[512 * 32];   // 32 KB
  __shared__ alignas(16) unsigned short p_lds[64 * PROW];  // 5 KB

  const int bid = blockIdx.x;
  const int xcd = bid & 7;
  const int b = xcd >> 1;                        // 2 XCDs per batch
  const int half = (bid >> 3) & 1;               // kv half
  const int qt = (bid >> 4) | ((xcd & 1) << 5);  // 0..63
  const int s0 = qt * 64;
  const int kvbase = half * 2048;
  const int tid = threadIdx.x;
  const int l = tid & 63, w = tid >> 6;
  const int qh = w >> 1, kh = w & 1;
  const int l31 = l & 31, h = l >> 5;
  const size_t boff = (size_t)b * 4096 * 512;

  // Q frags pinned: B-operand layout, q = s0+qh*32+l31, k = kh*256 + t*16 + h*8 + j
  bf16x8 qf[16];
  {
    const unsigned short* qrow =
        Q + boff + (size_t)(s0 + qh * 32 + l31) * 512 + kh * 256 + h * 8;
#pragma unroll
    for (int t = 0; t < 16; ++t) qf[t] = ld_frag(&qrow[t * 16]);
  }

  // O^T tiles: d = kh*256 + dt*32 + (r&3)+8*(r>>2)+4*h, q = qh*32+l31
  f32x16 o[8] = {};
  float m_run = -1e30f, l_run = 0.f;  // per-lane, q = l31 (replicated over h, kh)

  const unsigned short* Kbase = Kb + boff;
  const unsigned short* Vbase = Vt + (size_t)b * 512 * 4096;
  f32x4* exv = (f32x4*)k_lds;  // 4 waves * 4 rounds * 64 lanes * 16B = 16 KB

  for (int it = 0; it < 64; ++it) {
    __syncthreads();  // b1: prev PV/p_lds/ex reads done -> buffers free
    {
      const int kv0 = kvbase + it * 32;
#pragma unroll
      for (int i = 0; i < 8; ++i) {  // K: one 1KB row per wave per call
        const int row = i * 4 + w;
        gld_lds16(&Kbase[(size_t)(kv0 + row) * 512 + l * 8], &k_lds[row * KROW]);
      }
#pragma unroll
      for (int i = 0; i < 8; ++i) {  // Vt: XOR-swizzled kv-chunks
        const int dbase = (i * 4 + w) * 16;
        const int d = dbase + (l >> 2);
        const int jl = (l & 3) ^ ((d >> 1) & 3);
        gld_lds16(&Vbase[(size_t)d * 4096 + kv0 + jl * 8], &v_lds[dbase * 32]);
      }
    }
    __syncthreads();  // b2: staging complete

    // S^T partial over k-half kh: A = K[kv=l31][16k chunk], B = Q frag
    f32x16 acc0 = {}, acc1 = {};
#pragma unroll
    for (int t = 0; t < 16; t += 2) {
      bf16x8 kf0 = ld_frag(&k_lds[l31 * KROW + (kh * 16 + t) * 16 + h * 8]);
      bf16x8 kf1 = ld_frag(&k_lds[l31 * KROW + (kh * 16 + t + 1) * 16 + h * 8]);
      acc0 = MFMA32(kf0, qf[t], acc0);
      acc1 = MFMA32(kf1, qf[t + 1], acc1);
    }
    f32x16 ss = acc0 + acc1;
    __syncthreads();  // b3: all k_lds frag reads done (ex overlays k_lds)

    // exchange partial S with pair partner (w^1), sum
#pragma unroll
    for (int r4 = 0; r4 < 4; ++r4) {
      f32x4 t4;
      t4[0] = ss[r4 * 4 + 0]; t4[1] = ss[r4 * 4 + 1];
      t4[2] = ss[r4 * 4 + 2]; t4[3] = ss[r4 * 4 + 3];
      exv[(w * 4 + r4) * 64 + l] = t4;
    }
    __syncthreads();  // b4: partials visible
    {
      const int pw = w ^ 1;
#pragma unroll
      for (int r4 = 0; r4 < 4; ++r4) {
        f32x4 t4 = exv[(pw * 4 + r4) * 64 + l];
        ss[r4 * 4 + 0] += t4[0]; ss[r4 * 4 + 1] += t4[1];
        ss[r4 * 4 + 2] += t4[2]; ss[r4 * 4 + 3] += t4[3];
      }
    }

    // softmax: lane holds 16 kv for q=l31 (kv = (r&3)+8*(r>>2)+4h); 1 shuffle
    const float C1 = 0.125f * LOG2E;
    float m8 = ss[0];
#pragma unroll
    for (int r = 1; r < 16; ++r) m8 = fmaxf(m8, ss[r]);
    m8 = fmaxf(m8, __shfl_xor(m8, 32));
    const float mn = fmaxf(m_run, m8);

    float p[16], s8 = 0.f;
#pragma unroll
    for (int r = 0; r < 16; ++r) {
      p[r] = exp2f((ss[r] - mn) * C1);
      s8 += p[r];
    }
    s8 += __shfl_xor(s8, 32);

    // P^T write: wave kh writes its kv range [kh*16, kh*16+16)
    {
      unsigned short* prow = &p_lds[(qh * 32 + l31) * PROW];
      const int rb = kh * 8;
      ushort4 a4, b4;
      a4.x = f2bf(p[rb + 0]); a4.y = f2bf(p[rb + 1]);
      a4.z = f2bf(p[rb + 2]); a4.w = f2bf(p[rb + 3]);
      b4.x = f2bf(p[rb + 4]); b4.y = f2bf(p[rb + 5]);
      b4.z = f2bf(p[rb + 6]); b4.w = f2bf(p[rb + 7]);
      *(ushort4*)&prow[kh * 16 + 4 * h] = a4;       // regs r&3 -> kv +0..3
      *(ushort4*)&prow[kh * 16 + 8 + 4 * h] = b4;
    }

    if (__any(mn > m_run)) {
      const float alpha = exp2f((m_run - mn) * C1);
      l_run = l_run * alpha + s8;
      m_run = mn;
#pragma unroll
      for (int t = 0; t < 8; ++t)
#pragma unroll
        for (int e = 0; e < 16; ++e) o[t][e] *= alpha;
    } else {
      l_run += s8;
    }
    __syncthreads();  // b5: full P^T visible

    // O^T += V^T P^T : A = V frag (d-half kh), B = P frag (q-half qh)
    const bf16x8 pf0 = ld_frag(&p_lds[(qh * 32 + l31) * PROW + h * 8]);
    const bf16x8 pf1 = ld_frag(&p_lds[(qh * 32 + l31) * PROW + 16 + h * 8]);
#pragma unroll
    for (int dt = 0; dt < 8; ++dt) {
      const int d = kh * 256 + dt * 32 + l31;
      const int sw = (d >> 1) & 3;
      bf16x8 vf0 = ld_frag(&v_lds[d * 32 + (h ^ sw) * 8]);
      bf16x8 vf1 = ld_frag(&v_lds[d * 32 + ((2 + h) ^ sw) * 8]);
      o[dt] = MFMA32(vf0, pf0, o[dt]);
      o[dt] = MFMA32(vf1, pf1, o[dt]);
    }
  }

  // epilogue: normalized partial + (m,l) for the merge
  unsigned short* part = half ? part1 : part0;
  const float inv = 1.0f / l_run;
  unsigned short* orow = part + boff + (size_t)(s0 + qh * 32 + l31) * 512;
#pragma unroll
  for (int dt = 0; dt < 8; ++dt)
#pragma unroll
    for (int g = 0; g < 4; ++g) {
      ushort4 pk;
      pk.x = f2bf(o[dt][g * 4 + 0] * inv);
      pk.y = f2bf(o[dt][g * 4 + 1] * inv);
      pk.z = f2bf(o[dt][g * 4 + 2] * inv);
      pk.w = f2bf(o[dt][g * 4 + 3] * inv);
      *(ushort4*)&orow[kh * 256 + dt * 32 + g * 8 + 4 * h] = pk;
    }
  if (kh == 0 && l < 32) {
    float2 ml; ml.x = m_run; ml.y = l_run;
    mlbuf[(size_t)half * 16384 + b * 4096 + s0 + qh * 32 + l] = ml;
  }
}

// ---------------------------------------------------------------------------
// Merge the two kv-half streams: out = w0*P0 + w1*P1, w_h = l_h*2^((m_h-M)*C1)
// ---------------------------------------------------------------------------
__global__ void merge_halves(const unsigned short* __restrict__ p1,
                             const float2* __restrict__ mlbuf,
                             unsigned short* __restrict__ p0out) {
  const int i = blockIdx.x * blockDim.x + threadIdx.x;  // one per 8 elems
  const int row = i >> 6;
  const float2 a = mlbuf[row];
  const float2 bb = mlbuf[16384 + row];
  const float C1 = 0.125f * LOG2E;
  const float M = fmaxf(a.x, bb.x);
  float w0 = a.y * exp2f((a.x - M) * C1);
  float w1 = bb.y * exp2f((bb.x - M) * C1);
  const float inv = 1.0f / (w0 + w1);
  w0 *= inv; w1 *= inv;
  bf16x8 v0 = *(const bf16x8*)(p0out + (size_t)i * 8);
  bf16x8 v1 = *(const bf16x8*)(p1 + (size_t)i * 8);
  ushort4 o0, o1;
  o0.x = f2bf(w0 * (float)v0[0] + w1 * (float)v1[0]);
  o0.y = f2bf(w0 * (float)v0[1] + w1 * (float)v1[1]);
  o0.z = f2bf(w0 * (float)v0[2] + w1 * (float)v1[2]);
  o0.w = f2bf(w0 * (float)v0[3] + w1 * (float)v1[3]);
  o1.x = f2bf(w0 * (float)v0[4] + w1 * (float)v1[4]);
  o1.y = f2bf(w0 * (float)v0[5] + w1 * (float)v1[5]);
  o1.z = f2bf(w0 * (float)v0[6] + w1 * (float)v1[6]);
  o1.w = f2bf(w0 * (float)v0[7] + w1 * (float)v1[7]);
  *(ushort4*)(p0out + (size_t)i * 8) = o0;
  *(ushort4*)(p0out + (size_t)i * 8 + 4) = o1;
}

// ---------------------------------------------------------------------------
extern "C" void kernel_launch(void* const* d_in, const int* in_sizes, int n_in,
                              void* d_out, int out_size, void* d_ws, size_t ws_size,
                              hipStream_t stream) {
  const float* x = (const float*)d_in[0];      // [4,4096,512] fp32
  const float* w_in = (const float*)d_in[1];   // [1536,512] fp32
  const float* b_in = (const float*)d_in[2];   // [1536] fp32
  const float* w_out = (const float*)d_in[3];  // [512,512] fp32
  const float* b_out = (const float*)d_in[4];  // [512] fp32
  float* out = (float*)d_out;                  // [4,4096,512] fp32

  const size_t MTOT = (size_t)4 * 4096 * 512;  // 8,388,608
  unsigned short* q = (unsigned short*)d_ws;
  unsigned short* k = q + MTOT;
  unsigned short* vt = k + MTOT;       // [b][d][s]
  unsigned short* xbf = vt + MTOT;     // x bf16 -> attn part0 -> merged ao
  unsigned short* part1 = xbf + MTOT;  // attn part1
  unsigned short* w_in_bf = part1 + MTOT;
  unsigned short* w_out_bf = w_in_bf + 1536 * 512;
  float2* mlbuf = (float2*)(w_out_bf + 512 * 512);  // 2 x 16384 float2

  cvt_f2bf<<<dim3((int)(MTOT / 4 / 256)), 256, 0, stream>>>(x, xbf,
                                                            (int)(MTOT / 4));
  cvt_f2bf<<<dim3(768), 256, 0, stream>>>(w_in, w_in_bf, 1536 * 512 / 4);
  cvt_f2bf<<<dim3(256), 256, 0, stream>>>(w_out, w_out_bf, 512 * 512 / 4);

  gemm_bt<<<dim3(12, 128), 256, 0, stream>>>(xbf, w_in_bf, b_in, nullptr, q, k,
                                             vt, 16384, 1536, 512, 1);
  attn_kernel<<<dim3(512), 256, 0, stream>>>(q, k, vt, xbf, part1, mlbuf);
  merge_halves<<<dim3(4096), 256, 0, stream>>>(part1, mlbuf, xbf);
  gemm_bt<<<dim3(4, 128), 256, 0, stream>>>(xbf, w_out_bf, b_out, out, nullptr,
                                            nullptr, nullptr, 16384, 512, 512,
                                            0);
}